// Round 1
// baseline (300.207 us; speedup 1.0000x reference)
//
#include <hip/hip_runtime.h>
#include <hip/hip_bf16.h>
#include <math.h>

#define NTOK 8192
#define HID  1024
#define ISZ  256
#define NEXP 16
#define NBIG 4096  // NEXP*ISZ

typedef __attribute__((ext_vector_type(8))) short bf16x8;
typedef __attribute__((ext_vector_type(4))) float f32x4;

__device__ __forceinline__ unsigned short f2bf(float f) {
  unsigned u = __float_as_uint(f);
  u += 0x7fff + ((u >> 16) & 1);
  return (unsigned short)(u >> 16);
}

__device__ __forceinline__ void async16(void* l, const void* g) {
  __builtin_amdgcn_global_load_lds(
      (const __attribute__((address_space(1))) unsigned int*)g,
      (__attribute__((address_space(3))) unsigned int*)l, 16, 0, 0);
}

// ---------------- sim_matrix column inverse norms ----------------
__global__ void simnorm_kernel(const float* __restrict__ sm, float* __restrict__ inv_smn) {
  __shared__ float red[16][17];
  int t = threadIdx.x;
  int e = t & 15, g = t >> 4;  // 16 threads per expert column
  float ss = 0.f;
  for (int c = g; c < HID; c += 16) {
    float v = sm[c * NEXP + e];
    ss += v * v;
  }
  red[e][g] = ss;
  __syncthreads();
  if (t < 16) {
    float s = 0.f;
    #pragma unroll
    for (int i = 0; i < 16; i++) s += red[t][i];
    inv_smn[t] = 1.f / fmaxf(sqrtf(s), 1e-12f);
  }
}

// ---------------- gate: scores, k, routing weights, bf16 cast of x ----------------
__global__ __launch_bounds__(256)
void gate_kernel(const float* __restrict__ x, const float* __restrict__ sm,
                 const float* __restrict__ thr, const float* __restrict__ inv_smn,
                 float* __restrict__ scores_out, float* __restrict__ k_out,
                 float* __restrict__ rw_out, unsigned short* __restrict__ xb_out) {
  const int n = blockIdx.x;
  const int t = threadIdx.x;
  const int lane = t & 63, wave = t >> 6;
  const float* xr = x + (size_t)n * HID;

  float p[16];
  #pragma unroll
  for (int e = 0; e < 16; e++) p[e] = 0.f;
  float ss = 0.f;

  #pragma unroll
  for (int q = 0; q < 4; q++) {
    int c = t + q * 256;
    float v = xr[c];
    ss += v * v;
    xb_out[(size_t)n * HID + c] = f2bf(v);
    const float4* smr = (const float4*)(sm + (size_t)c * NEXP);
    float4 s0 = smr[0], s1 = smr[1], s2 = smr[2], s3 = smr[3];
    p[0] += v * s0.x;  p[1] += v * s0.y;  p[2] += v * s0.z;  p[3] += v * s0.w;
    p[4] += v * s1.x;  p[5] += v * s1.y;  p[6] += v * s1.z;  p[7] += v * s1.w;
    p[8] += v * s2.x;  p[9] += v * s2.y;  p[10] += v * s2.z; p[11] += v * s2.w;
    p[12] += v * s3.x; p[13] += v * s3.y; p[14] += v * s3.z; p[15] += v * s3.w;
  }

  // wave-level reduce (64 lanes) of 17 values
  #pragma unroll
  for (int off = 32; off > 0; off >>= 1) {
    ss += __shfl_down(ss, off, 64);
    #pragma unroll
    for (int e = 0; e < 16; e++) p[e] += __shfl_down(p[e], off, 64);
  }

  __shared__ float red[4][17];
  __shared__ float sc[16];
  if (lane == 0) {
    red[wave][0] = ss;
    #pragma unroll
    for (int e = 0; e < 16; e++) red[wave][1 + e] = p[e];
  }
  __syncthreads();

  if (t < 16) {
    float d = red[0][1 + t] + red[1][1 + t] + red[2][1 + t] + red[3][1 + t];
    float ssum = red[0][0] + red[1][0] + red[2][0] + red[3][0];
    float inv_x = 1.f / fmaxf(sqrtf(ssum), 1e-12f);
    float s = d * inv_x * inv_smn[t];
    scores_out[(size_t)n * 16 + t] = s;
    sc[t] = s;
  }
  __syncthreads();

  if (t < 16) {
    float thrv = thr[0];
    float s = sc[t];
    bool act = s > thrv;
    float m = act ? s : -INFINITY;
    int cnt = act ? 1 : 0;
    #pragma unroll
    for (int off = 8; off > 0; off >>= 1) {
      m = fmaxf(m, __shfl_xor(m, off, 16));
      cnt += __shfl_xor(cnt, off, 16);
    }
    float pv;
    if (cnt > 0) pv = act ? expf(s - m) : 0.f;
    else         pv = 1.f;  // softmax of all-equal NEG_INF -> uniform
    float sum = pv;
    #pragma unroll
    for (int off = 8; off > 0; off >>= 1) sum += __shfl_xor(sum, off, 16);
    rw_out[(size_t)n * 16 + t] = pv / sum;
    if (t == 0) k_out[n] = (float)cnt;
  }
}

// ---------------- transpose + bf16 cast (per-expert 2D transpose) ----------------
// src: expert e at src + e*e_src_stride, shape [R][C] row-major f32.
// dst element for (row r, col cc): dst[cc*dstride + e*e_dst_mult + r] = src[r*C+cc]
__global__ __launch_bounds__(256)
void transpose_cast_kernel(const float* __restrict__ src, unsigned short* __restrict__ dst,
                           int R, int C, int dstride, int e_src_stride, int e_dst_mult) {
  __shared__ float tile[32][33];
  const int e = blockIdx.z;
  const int r0 = blockIdx.y * 32, c0 = blockIdx.x * 32;
  const int tx = threadIdx.x & 31, ty = threadIdx.x >> 5;  // 32 x 8
  const float* s = src + (size_t)e * e_src_stride;
  #pragma unroll
  for (int q = 0; q < 4; q++) {
    int r = r0 + ty + q * 8;
    tile[ty + q * 8][tx] = s[(size_t)r * C + c0 + tx];
  }
  __syncthreads();
  unsigned short* d = dst + (size_t)e * e_dst_mult;
  #pragma unroll
  for (int q = 0; q < 4; q++) {
    int cc = c0 + ty + q * 8;   // dst row index (src col)
    int r  = r0 + tx;           // dst col index (src row)
    d[(size_t)cc * dstride + r] = f2bf(tile[tx][ty + q * 8]);
  }
}

// ---------------- 128x128 bf16 MFMA GEMM, B^T layout ----------------
// A: [M][K] bf16, B: [Nn][K] bf16. EPI==1: Cb[r*Nn+col] = bf16(gelu(v)*rw[r][col>>8])
// EPI==2: Cf[r*Nn+col] = v
template <int EPI>
__global__ __launch_bounds__(256)
void gemm_bt(const unsigned short* __restrict__ A, const unsigned short* __restrict__ B,
             float* __restrict__ Cf, unsigned short* __restrict__ Cb,
             const float* __restrict__ rw, int M, int Nn, int K) {
  __shared__ unsigned short As[128 * 32];
  __shared__ unsigned short Bs[128 * 32];
  const int t = threadIdx.x, lane = t & 63, wave = t >> 6;
  const int wr = wave >> 1, wc = wave & 1;
  const int bm = blockIdx.y, bn = blockIdx.x;

  f32x4 acc[4][4];
  #pragma unroll
  for (int i = 0; i < 4; i++)
    #pragma unroll
    for (int j = 0; j < 4; j++) acc[i][j] = (f32x4){0.f, 0.f, 0.f, 0.f};

  const int srow = wave * 32 + (lane >> 2);
  const int skol = (lane & 3) * 8;
  const unsigned short* gA = A + (size_t)(bm * 128 + srow) * K + skol;
  const unsigned short* gB = B + (size_t)(bn * 128 + srow) * K + skol;
  unsigned short* lA0 = &As[(wave * 32) * 32];
  unsigned short* lA1 = &As[(wave * 32 + 16) * 32];
  unsigned short* lB0 = &Bs[(wave * 32) * 32];
  unsigned short* lB1 = &Bs[(wave * 32 + 16) * 32];

  const int lr = lane & 15, lk = (lane >> 4) * 8;

  for (int k0 = 0; k0 < K; k0 += 32) {
    async16(lA0, gA + k0);
    async16(lA1, gA + (size_t)16 * K + k0);
    async16(lB0, gB + k0);
    async16(lB1, gB + (size_t)16 * K + k0);
    __syncthreads();

    bf16x8 af[4], bfr[4];
    #pragma unroll
    for (int m = 0; m < 4; m++) af[m] = *(const bf16x8*)&As[(wr * 64 + m * 16 + lr) * 32 + lk];
    #pragma unroll
    for (int n = 0; n < 4; n++) bfr[n] = *(const bf16x8*)&Bs[(wc * 64 + n * 16 + lr) * 32 + lk];
    #pragma unroll
    for (int m = 0; m < 4; m++)
      #pragma unroll
      for (int n = 0; n < 4; n++)
        acc[m][n] = __builtin_amdgcn_mfma_f32_16x16x32_bf16(af[m], bfr[n], acc[m][n], 0, 0, 0);
    __syncthreads();
  }

  // epilogue: C/D layout col=lane&15, row=(lane>>4)*4+j
  #pragma unroll
  for (int m = 0; m < 4; m++) {
    #pragma unroll
    for (int n = 0; n < 4; n++) {
      int row0 = bm * 128 + wr * 64 + m * 16 + (lane >> 4) * 4;
      int col  = bn * 128 + wc * 64 + n * 16 + lr;
      #pragma unroll
      for (int j = 0; j < 4; j++) {
        float v = acc[m][n][j];
        int r = row0 + j;
        if (EPI == 1) {
          float ge = 0.5f * v * (1.f + erff(v * 0.70710678118654752f));
          float w = rw[(size_t)r * 16 + (col >> 8)];
          Cb[(size_t)r * Nn + col] = f2bf(ge * w);
        } else {
          Cf[(size_t)r * Nn + col] = v;
        }
      }
    }
  }
}

extern "C" void kernel_launch(void* const* d_in, const int* in_sizes, int n_in,
                              void* d_out, int out_size, void* d_ws, size_t ws_size,
                              hipStream_t stream) {
  const float* x   = (const float*)d_in[0];  // [4,2048,1024]
  const float* sm  = (const float*)d_in[1];  // [1024,16]
  const float* thr = (const float*)d_in[2];  // [1]
  const float* w1  = (const float*)d_in[3];  // [16,1024,256]
  const float* w2  = (const float*)d_in[4];  // [16,256,1024]

  float* out_final  = (float*)d_out;                     // 8192*1024
  float* out_scores = out_final + (size_t)NTOK * HID;    // 8192*16
  float* out_k      = out_scores + (size_t)NTOK * NEXP;  // 8192

  char* ws = (char*)d_ws;
  float* inv_smn = (float*)ws;                                   // 64 B (pad to 256)
  float* rwbuf   = (float*)(ws + 256);                           // 8192*16*4 = 512 KiB
  unsigned short* Xb  = (unsigned short*)(ws + 256 + 524288);    // 8192*1024*2 = 16 MiB
  unsigned short* W1T = Xb + (size_t)NTOK * HID;                 // [4096][1024] bf16
  unsigned short* W2T = W1T + (size_t)NBIG * HID;                // [1024][4096] bf16
  unsigned short* H   = W2T + (size_t)HID * NBIG;                // [8192][4096] bf16

  simnorm_kernel<<<1, 256, 0, stream>>>(sm, inv_smn);
  gate_kernel<<<NTOK, 256, 0, stream>>>(x, sm, thr, inv_smn, out_scores, out_k, rwbuf, Xb);
  // w1 [e][c][i] -> W1T[(e*256+i)*1024 + c]: per-expert transpose of [1024][256]
  transpose_cast_kernel<<<dim3(ISZ / 32, HID / 32, NEXP), 256, 0, stream>>>(
      w1, W1T, HID, ISZ, HID, HID * ISZ, ISZ * HID);
  // w2 [e][i][c] -> W2T[c*4096 + e*256 + i]: per-expert transpose of [256][1024]
  transpose_cast_kernel<<<dim3(HID / 32, ISZ / 32, NEXP), 256, 0, stream>>>(
      w2, W2T, ISZ, HID, NBIG, ISZ * HID, ISZ);
  // H = gelu(Xb @ W1T^T) * rw   [8192 x 4096]
  gemm_bt<1><<<dim3(NBIG / 128, NTOK / 128), 256, 0, stream>>>(
      Xb, W1T, nullptr, H, rwbuf, NTOK, NBIG, HID);
  // final = H @ W2T^T            [8192 x 1024]
  gemm_bt<2><<<dim3(HID / 128, NTOK / 128), 256, 0, stream>>>(
      H, W2T, out_final, nullptr, nullptr, NTOK, HID, NBIG);
}

// Round 2
// 271.250 us; speedup vs baseline: 1.1068x; 1.1068x over previous
//
#include <hip/hip_runtime.h>
#include <hip/hip_bf16.h>
#include <math.h>

#define NTOK 8192
#define HID  1024
#define ISZ  256
#define NEXP 16
#define NBIG 4096  // NEXP*ISZ

typedef __attribute__((ext_vector_type(8))) short bf16x8;
typedef __attribute__((ext_vector_type(4))) float f32x4;

__device__ __forceinline__ unsigned short f2bf(float f) {
  unsigned u = __float_as_uint(f);
  u += 0x7fff + ((u >> 16) & 1);
  return (unsigned short)(u >> 16);
}

__device__ __forceinline__ void async16(void* l, const void* g) {
  __builtin_amdgcn_global_load_lds(
      (const __attribute__((address_space(1))) unsigned int*)g,
      (__attribute__((address_space(3))) unsigned int*)l, 16, 0, 0);
}

// ---------------- sim_matrix column inverse norms ----------------
__global__ void simnorm_kernel(const float* __restrict__ sm, float* __restrict__ inv_smn) {
  __shared__ float red[16][17];
  int t = threadIdx.x;
  int e = t & 15, g = t >> 4;
  float ss = 0.f;
  for (int c = g; c < HID; c += 16) {
    float v = sm[c * NEXP + e];
    ss += v * v;
  }
  red[e][g] = ss;
  __syncthreads();
  if (t < 16) {
    float s = 0.f;
    #pragma unroll
    for (int i = 0; i < 16; i++) s += red[t][i];
    inv_smn[t] = 1.f / fmaxf(sqrtf(s), 1e-12f);
  }
}

// ---------------- gate: scores, k, routing weights, bf16 cast of x ----------------
__global__ __launch_bounds__(256)
void gate_kernel(const float* __restrict__ x, const float* __restrict__ sm,
                 const float* __restrict__ thr, const float* __restrict__ inv_smn,
                 float* __restrict__ scores_out, float* __restrict__ k_out,
                 float* __restrict__ rw_out, unsigned short* __restrict__ xb_out) {
  const int n = blockIdx.x;
  const int t = threadIdx.x;
  const int lane = t & 63, wave = t >> 6;
  const float* xr = x + (size_t)n * HID;

  float p[16];
  #pragma unroll
  for (int e = 0; e < 16; e++) p[e] = 0.f;
  float ss = 0.f;

  #pragma unroll
  for (int q = 0; q < 4; q++) {
    int c = t + q * 256;
    float v = xr[c];
    ss += v * v;
    xb_out[(size_t)n * HID + c] = f2bf(v);
    const float4* smr = (const float4*)(sm + (size_t)c * NEXP);
    float4 s0 = smr[0], s1 = smr[1], s2 = smr[2], s3 = smr[3];
    p[0] += v * s0.x;  p[1] += v * s0.y;  p[2] += v * s0.z;  p[3] += v * s0.w;
    p[4] += v * s1.x;  p[5] += v * s1.y;  p[6] += v * s1.z;  p[7] += v * s1.w;
    p[8] += v * s2.x;  p[9] += v * s2.y;  p[10] += v * s2.z; p[11] += v * s2.w;
    p[12] += v * s3.x; p[13] += v * s3.y; p[14] += v * s3.z; p[15] += v * s3.w;
  }

  #pragma unroll
  for (int off = 32; off > 0; off >>= 1) {
    ss += __shfl_down(ss, off, 64);
    #pragma unroll
    for (int e = 0; e < 16; e++) p[e] += __shfl_down(p[e], off, 64);
  }

  __shared__ float red[4][17];
  __shared__ float sc[16];
  if (lane == 0) {
    red[wave][0] = ss;
    #pragma unroll
    for (int e = 0; e < 16; e++) red[wave][1 + e] = p[e];
  }
  __syncthreads();

  if (t < 16) {
    float d = red[0][1 + t] + red[1][1 + t] + red[2][1 + t] + red[3][1 + t];
    float ssum = red[0][0] + red[1][0] + red[2][0] + red[3][0];
    float inv_x = 1.f / fmaxf(sqrtf(ssum), 1e-12f);
    float s = d * inv_x * inv_smn[t];
    scores_out[(size_t)n * 16 + t] = s;
    sc[t] = s;
  }
  __syncthreads();

  if (t < 16) {
    float thrv = thr[0];
    float s = sc[t];
    bool act = s > thrv;
    float m = act ? s : -INFINITY;
    int cnt = act ? 1 : 0;
    #pragma unroll
    for (int off = 8; off > 0; off >>= 1) {
      m = fmaxf(m, __shfl_xor(m, off, 16));
      cnt += __shfl_xor(cnt, off, 16);
    }
    float pv;
    if (cnt > 0) pv = act ? expf(s - m) : 0.f;
    else         pv = 1.f;
    float sum = pv;
    #pragma unroll
    for (int off = 8; off > 0; off >>= 1) sum += __shfl_xor(sum, off, 16);
    rw_out[(size_t)n * 16 + t] = pv / sum;
    if (t == 0) k_out[n] = (float)cnt;
  }
}

// ---------------- transpose + bf16 cast (per-expert 2D transpose) ----------------
__global__ __launch_bounds__(256)
void transpose_cast_kernel(const float* __restrict__ src, unsigned short* __restrict__ dst,
                           int R, int C, int dstride, int e_src_stride, int e_dst_mult) {
  __shared__ float tile[32][33];
  const int e = blockIdx.z;
  const int r0 = blockIdx.y * 32, c0 = blockIdx.x * 32;
  const int tx = threadIdx.x & 31, ty = threadIdx.x >> 5;
  const float* s = src + (size_t)e * e_src_stride;
  #pragma unroll
  for (int q = 0; q < 4; q++) {
    int r = r0 + ty + q * 8;
    tile[ty + q * 8][tx] = s[(size_t)r * C + c0 + tx];
  }
  __syncthreads();
  unsigned short* d = dst + (size_t)e * e_dst_mult;
  #pragma unroll
  for (int q = 0; q < 4; q++) {
    int cc = c0 + ty + q * 8;
    int r  = r0 + tx;
    d[(size_t)cc * dstride + r] = f2bf(tile[tx][ty + q * 8]);
  }
}

// ================= 256x256 8-wave 4-phase pipelined MFMA GEMM =================
// A: [M][K] bf16 row-major, B: [N][K] bf16 row-major (B^T input). C = A @ B^T.
// LDS 128 KiB: A region [2 buf][2 qm][2 wm][64 r][128 B] at byte 0,
//              B region [2 buf][2 qn][4 wn][32 r][128 B] at byte 65536.
// Content swizzle: colbyte ^= (r&7)<<4 (applied on global SOURCE addr at stage
// time — DMA dest stays linear — and identically on the ds_read side).
// Per K-tile (BK=64): 4 phases, phase p=(qm=p&1, qn=p>>1) computes quadrant
// (m in qm*4..+3, n in qn*2..+1, kk=0..1) = 16 MFMA, stages 1 unit of tile t+1
// into buf^1 (order A0,B0,A1,B1), counted vmcnt(4) before b2 at phases 0,1,3.
#define PHASE(QM, QN, SU, WAIT_)                                                      \
  {                                                                                   \
    bf16x8 afr[4][2], bfr[2][2];                                                      \
    _Pragma("unroll")                                                                 \
    for (int ml = 0; ml < 4; ml++) {                                                  \
      afr[ml][0] = *(const bf16x8*)(bufA + (QM)*16384 + wmo + ml*2048 + lro + colk0); \
      afr[ml][1] = *(const bf16x8*)(bufA + (QM)*16384 + wmo + ml*2048 + lro + colk1); \
    }                                                                                 \
    _Pragma("unroll")                                                                 \
    for (int nl = 0; nl < 2; nl++) {                                                  \
      bfr[nl][0] = *(const bf16x8*)(bufB + (QN)*16384 + wno + nl*2048 + lro + colk0); \
      bfr[nl][1] = *(const bf16x8*)(bufB + (QN)*16384 + wno + nl*2048 + lro + colk1); \
    }                                                                                 \
    _Pragma("unroll")                                                                 \
    for (int i = 0; i < 2; i++) {                                                     \
      if ((SU) == 0) async16(ldsAn + o16[i],         Ag + (size_t)aRow[i]*K + kn + aCol[i]);        \
      if ((SU) == 1) async16(ldsBn + o16[i],         Bg + (size_t)bRow[i]*K + kn + bCol[i]);        \
      if ((SU) == 2) async16(ldsAn + 16384 + o16[i], Ag + (size_t)(aRow[i] + 64)*K + kn + aCol[i]); \
      if ((SU) == 3) async16(ldsBn + 16384 + o16[i], Bg + (size_t)(bRow[i] + 32)*K + kn + bCol[i]); \
    }                                                                                 \
    __builtin_amdgcn_sched_barrier(0);                                                \
    __builtin_amdgcn_s_barrier();                                                     \
    asm volatile("s_waitcnt lgkmcnt(0)" ::: "memory");                                \
    __builtin_amdgcn_sched_barrier(0);                                                \
    __builtin_amdgcn_s_setprio(1);                                                    \
    _Pragma("unroll")                                                                 \
    for (int ml = 0; ml < 4; ml++)                                                    \
      _Pragma("unroll")                                                               \
      for (int nl = 0; nl < 2; nl++) {                                                \
        acc[(QM)*4+ml][(QN)*2+nl] = __builtin_amdgcn_mfma_f32_16x16x32_bf16(          \
            afr[ml][0], bfr[nl][0], acc[(QM)*4+ml][(QN)*2+nl], 0, 0, 0);              \
        acc[(QM)*4+ml][(QN)*2+nl] = __builtin_amdgcn_mfma_f32_16x16x32_bf16(          \
            afr[ml][1], bfr[nl][1], acc[(QM)*4+ml][(QN)*2+nl], 0, 0, 0);              \
      }                                                                               \
    __builtin_amdgcn_s_setprio(0);                                                    \
    __builtin_amdgcn_sched_barrier(0);                                                \
    if (WAIT_) { asm volatile("s_waitcnt vmcnt(4)" ::: "memory"); }                   \
    __builtin_amdgcn_s_barrier();                                                     \
  }

template <int EPI, int K, int NBN>
__global__ __launch_bounds__(512, 2)
void gemm256(const unsigned short* __restrict__ A, const unsigned short* __restrict__ B,
             float* __restrict__ Cf, unsigned short* __restrict__ Cb,
             const float* __restrict__ rw) {
  __shared__ __align__(1024) char lds[131072];
  constexpr int NT = K / 64;
  const int tid = threadIdx.x;
  const int lane = tid & 63, wid = tid >> 6;
  const int wm = wid >> 2, wn = wid & 3;
  const int lr = lane & 15;

  // bijective XCD swizzle (gridDim.x % 8 == 0 for both instantiations)
  const int nwg = gridDim.x;
  const int cpx = nwg >> 3;
  const int wg = (blockIdx.x & 7) * cpx + (blockIdx.x >> 3);
  const int bm = wg / NBN, bn = wg % NBN;

  // ds_read per-thread constants
  const int swz = (lr & 7) << 4;
  const int colk0 = ((lane >> 4) * 16) ^ swz;
  const int colk1 = (64 + (lane >> 4) * 16) ^ swz;
  const int wmo = wm * 8192, wno = wn * 4096, lro = lr * 128;

  // staging decode (linear LDS dest, inverse-swizzled global source)
  int aRow[2], aCol[2], bRow[2], bCol[2], o16[2];
  #pragma unroll
  for (int i = 0; i < 2; i++) {
    int o = (i * 512 + tid) * 16;
    o16[i] = o;
    { int wmb = o >> 13, ob = o & 8191, r = ob >> 7, cb = ob & 127;
      aRow[i] = wmb * 128 + r; aCol[i] = (cb ^ ((r & 7) << 4)) >> 1; }
    { int wnb = o >> 12, ob = o & 4095, r = ob >> 7, cb = ob & 127;
      bRow[i] = wnb * 64 + r; bCol[i] = (cb ^ ((r & 7) << 4)) >> 1; }
  }

  const unsigned short* Ag = A + (size_t)bm * 256 * K;
  const unsigned short* Bg = B + (size_t)bn * 256 * K;

  f32x4 acc[8][4];
  #pragma unroll
  for (int m = 0; m < 8; m++)
    #pragma unroll
    for (int n = 0; n < 4; n++) acc[m][n] = (f32x4){0.f, 0.f, 0.f, 0.f};

  // prologue: stage tile 0 into buf0 (unit order A0,B0,A1,B1), drain, barrier
  #pragma unroll
  for (int i = 0; i < 2; i++) async16(lds + o16[i],                 Ag + (size_t)aRow[i] * K + aCol[i]);
  #pragma unroll
  for (int i = 0; i < 2; i++) async16(lds + 65536 + o16[i],         Bg + (size_t)bRow[i] * K + bCol[i]);
  #pragma unroll
  for (int i = 0; i < 2; i++) async16(lds + 16384 + o16[i],         Ag + (size_t)(aRow[i] + 64) * K + aCol[i]);
  #pragma unroll
  for (int i = 0; i < 2; i++) async16(lds + 65536 + 16384 + o16[i], Bg + (size_t)(bRow[i] + 32) * K + bCol[i]);
  asm volatile("s_waitcnt vmcnt(0)" ::: "memory");
  __builtin_amdgcn_s_barrier();

  #pragma unroll 1
  for (int t = 0; t < NT; t += 2) {
    {
      const char* bufA = lds;               // cur buf0
      const char* bufB = lds + 65536;
      char* ldsAn = lds + 32768;            // stage into buf1
      char* ldsBn = lds + 65536 + 32768;
      const int kn = ((t + 1) & (NT - 1)) << 6;
      PHASE(0, 0, 0, 1)
      PHASE(1, 0, 1, 1)
      PHASE(0, 1, 2, 0)
      PHASE(1, 1, 3, 1)
    }
    {
      const char* bufA = lds + 32768;       // cur buf1
      const char* bufB = lds + 65536 + 32768;
      char* ldsAn = lds;                    // stage into buf0
      char* ldsBn = lds + 65536;
      const int kn = ((t + 2) & (NT - 1)) << 6;
      PHASE(0, 0, 0, 1)
      PHASE(1, 0, 1, 1)
      PHASE(0, 1, 2, 0)
      PHASE(1, 1, 3, 1)
    }
  }

  asm volatile("s_waitcnt vmcnt(0)" ::: "memory");

  // epilogue: C/D layout col=lane&15, row=(lane>>4)*4+j
  const int jr = (lane >> 4) * 4;
  if (EPI == 1) {
    float wrow[8][4];
    #pragma unroll
    for (int m = 0; m < 8; m++)
      #pragma unroll
      for (int j = 0; j < 4; j++)
        wrow[m][j] = rw[(size_t)(bm * 256 + wm * 128 + m * 16 + jr + j) * 16 + bn];
    #pragma unroll
    for (int m = 0; m < 8; m++) {
      #pragma unroll
      for (int n = 0; n < 4; n++) {
        int col = bn * 256 + wn * 64 + n * 16 + lr;
        #pragma unroll
        for (int j = 0; j < 4; j++) {
          int r = bm * 256 + wm * 128 + m * 16 + jr + j;
          float v = acc[m][n][j];
          float g = 0.7978845608f * (v + 0.044715f * v * v * v);
          float e = __expf(2.f * g);
          float th = 1.f - 2.f / (e + 1.f);   // tanh(g), inf-safe
          float ge = 0.5f * v * (1.f + th);
          Cb[(size_t)r * NBIG + col] = f2bf(ge * wrow[m][j]);
        }
      }
    }
  } else {
    #pragma unroll
    for (int m = 0; m < 8; m++) {
      #pragma unroll
      for (int n = 0; n < 4; n++) {
        int col = bn * 256 + wn * 64 + n * 16 + lr;
        #pragma unroll
        for (int j = 0; j < 4; j++) {
          int r = bm * 256 + wm * 128 + m * 16 + jr + j;
          Cf[(size_t)r * HID + col] = acc[m][n][j];
        }
      }
    }
  }
}

extern "C" void kernel_launch(void* const* d_in, const int* in_sizes, int n_in,
                              void* d_out, int out_size, void* d_ws, size_t ws_size,
                              hipStream_t stream) {
  const float* x   = (const float*)d_in[0];
  const float* sm  = (const float*)d_in[1];
  const float* thr = (const float*)d_in[2];
  const float* w1  = (const float*)d_in[3];
  const float* w2  = (const float*)d_in[4];

  float* out_final  = (float*)d_out;
  float* out_scores = out_final + (size_t)NTOK * HID;
  float* out_k      = out_scores + (size_t)NTOK * NEXP;

  char* ws = (char*)d_ws;
  float* inv_smn = (float*)ws;
  float* rwbuf   = (float*)(ws + 256);
  unsigned short* Xb  = (unsigned short*)(ws + 256 + 524288);
  unsigned short* W1T = Xb + (size_t)NTOK * HID;      // [4096][1024] bf16
  unsigned short* W2T = W1T + (size_t)NBIG * HID;     // [1024][4096] bf16
  unsigned short* H   = W2T + (size_t)HID * NBIG;     // [8192][4096] bf16

  simnorm_kernel<<<1, 256, 0, stream>>>(sm, inv_smn);
  gate_kernel<<<NTOK, 256, 0, stream>>>(x, sm, thr, inv_smn, out_scores, out_k, rwbuf, Xb);
  transpose_cast_kernel<<<dim3(ISZ / 32, HID / 32, NEXP), 256, 0, stream>>>(
      w1, W1T, HID, ISZ, HID, HID * ISZ, ISZ * HID);
  transpose_cast_kernel<<<dim3(HID / 32, ISZ / 32, NEXP), 256, 0, stream>>>(
      w2, W2T, ISZ, HID, NBIG, ISZ * HID, ISZ);
  // H = gelu(Xb @ W1T^T) * rw   [8192 x 4096], 512 blocks
  gemm256<1, HID, 16><<<512, 512, 0, stream>>>(Xb, W1T, nullptr, H, rwbuf);
  // final = H @ W2T^T            [8192 x 1024], 128 blocks
  gemm256<2, NBIG, 4><<<128, 512, 0, stream>>>(H, W2T, out_final, nullptr, nullptr);
}

// Round 4
// 242.469 us; speedup vs baseline: 1.2381x; 1.1187x over previous
//
#include <hip/hip_runtime.h>
#include <hip/hip_bf16.h>
#include <math.h>

#define NTOK 8192
#define HID  1024
#define ISZ  256
#define NEXP 16
#define NBIG 4096  // NEXP*ISZ

typedef __attribute__((ext_vector_type(8))) short bf16x8;
typedef __attribute__((ext_vector_type(4))) float f32x4;

__device__ __forceinline__ unsigned short f2bf(float f) {
  unsigned u = __float_as_uint(f);
  u += 0x7fff + ((u >> 16) & 1);
  return (unsigned short)(u >> 16);
}

__device__ __forceinline__ void async16(void* l, const void* g) {
  __builtin_amdgcn_global_load_lds(
      (const __attribute__((address_space(1))) unsigned int*)g,
      (__attribute__((address_space(3))) unsigned int*)l, 16, 0, 0);
}

// ---------------- sim_matrix column inverse norms ----------------
__global__ void simnorm_kernel(const float* __restrict__ sm, float* __restrict__ inv_smn) {
  __shared__ float red[16][17];
  int t = threadIdx.x;
  int e = t & 15, g = t >> 4;
  float ss = 0.f;
  for (int c = g; c < HID; c += 16) {
    float v = sm[c * NEXP + e];
    ss += v * v;
  }
  red[e][g] = ss;
  __syncthreads();
  if (t < 16) {
    float s = 0.f;
    #pragma unroll
    for (int i = 0; i < 16; i++) s += red[t][i];
    inv_smn[t] = 1.f / fmaxf(sqrtf(s), 1e-12f);
  }
}

// ---------------- gate: scores, k, routing weights, bf16 cast of x ----------------
__global__ __launch_bounds__(256)
void gate_kernel(const float* __restrict__ x, const float* __restrict__ sm,
                 const float* __restrict__ thr, const float* __restrict__ inv_smn,
                 float* __restrict__ scores_out, float* __restrict__ k_out,
                 float* __restrict__ rw_out, unsigned short* __restrict__ xb_out) {
  const int n = blockIdx.x;
  const int t = threadIdx.x;
  const int lane = t & 63, wave = t >> 6;
  const float* xr = x + (size_t)n * HID;

  float p[16];
  #pragma unroll
  for (int e = 0; e < 16; e++) p[e] = 0.f;
  float ss = 0.f;

  #pragma unroll
  for (int q = 0; q < 4; q++) {
    int c = t + q * 256;
    float v = xr[c];
    ss += v * v;
    xb_out[(size_t)n * HID + c] = f2bf(v);
    const float4* smr = (const float4*)(sm + (size_t)c * NEXP);
    float4 s0 = smr[0], s1 = smr[1], s2 = smr[2], s3 = smr[3];
    p[0] += v * s0.x;  p[1] += v * s0.y;  p[2] += v * s0.z;  p[3] += v * s0.w;
    p[4] += v * s1.x;  p[5] += v * s1.y;  p[6] += v * s1.z;  p[7] += v * s1.w;
    p[8] += v * s2.x;  p[9] += v * s2.y;  p[10] += v * s2.z; p[11] += v * s2.w;
    p[12] += v * s3.x; p[13] += v * s3.y; p[14] += v * s3.z; p[15] += v * s3.w;
  }

  #pragma unroll
  for (int off = 32; off > 0; off >>= 1) {
    ss += __shfl_down(ss, off, 64);
    #pragma unroll
    for (int e = 0; e < 16; e++) p[e] += __shfl_down(p[e], off, 64);
  }

  __shared__ float red[4][17];
  __shared__ float sc[16];
  if (lane == 0) {
    red[wave][0] = ss;
    #pragma unroll
    for (int e = 0; e < 16; e++) red[wave][1 + e] = p[e];
  }
  __syncthreads();

  if (t < 16) {
    float d = red[0][1 + t] + red[1][1 + t] + red[2][1 + t] + red[3][1 + t];
    float ssum = red[0][0] + red[1][0] + red[2][0] + red[3][0];
    float inv_x = 1.f / fmaxf(sqrtf(ssum), 1e-12f);
    float s = d * inv_x * inv_smn[t];
    scores_out[(size_t)n * 16 + t] = s;
    sc[t] = s;
  }
  __syncthreads();

  if (t < 16) {
    float thrv = thr[0];
    float s = sc[t];
    bool act = s > thrv;
    float m = act ? s : -INFINITY;
    int cnt = act ? 1 : 0;
    #pragma unroll
    for (int off = 8; off > 0; off >>= 1) {
      m = fmaxf(m, __shfl_xor(m, off, 16));
      cnt += __shfl_xor(cnt, off, 16);
    }
    float pv;
    if (cnt > 0) pv = act ? expf(s - m) : 0.f;
    else         pv = 1.f;
    float sum = pv;
    #pragma unroll
    for (int off = 8; off > 0; off >>= 1) sum += __shfl_xor(sum, off, 16);
    rw_out[(size_t)n * 16 + t] = pv / sum;
    if (t == 0) k_out[n] = (float)cnt;
  }
}

// ---------------- transpose + bf16 cast (per-expert 2D transpose) ----------------
__global__ __launch_bounds__(256)
void transpose_cast_kernel(const float* __restrict__ src, unsigned short* __restrict__ dst,
                           int R, int C, int dstride, int e_src_stride, int e_dst_mult) {
  __shared__ float tile[32][33];
  const int e = blockIdx.z;
  const int r0 = blockIdx.y * 32, c0 = blockIdx.x * 32;
  const int tx = threadIdx.x & 31, ty = threadIdx.x >> 5;
  const float* s = src + (size_t)e * e_src_stride;
  #pragma unroll
  for (int q = 0; q < 4; q++) {
    int r = r0 + ty + q * 8;
    tile[ty + q * 8][tx] = s[(size_t)r * C + c0 + tx];
  }
  __syncthreads();
  unsigned short* d = dst + (size_t)e * e_dst_mult;
  #pragma unroll
  for (int q = 0; q < 4; q++) {
    int cc = c0 + ty + q * 8;
    int r  = r0 + tx;
    d[(size_t)cc * dstride + r] = f2bf(tile[tx][ty + q * 8]);
  }
}

// ================= 256x256 8-wave 4-phase pipelined MFMA GEMM =================
// VERIFIED round-2 schedule (passed graph-replay validation) — do not alter
// sync structure. A: [.][LD] bf16, B: [.][LD] bf16 (B^T input). C = A @ B^T
// over KEXT columns starting at the passed base pointers.
#define PHASE(QM, QN, SU, WAIT_)                                                      \
  {                                                                                   \
    bf16x8 afr[4][2], bfr[2][2];                                                      \
    _Pragma("unroll")                                                                 \
    for (int ml = 0; ml < 4; ml++) {                                                  \
      afr[ml][0] = *(const bf16x8*)(bufA + (QM)*16384 + wmo + ml*2048 + lro + colk0); \
      afr[ml][1] = *(const bf16x8*)(bufA + (QM)*16384 + wmo + ml*2048 + lro + colk1); \
    }                                                                                 \
    _Pragma("unroll")                                                                 \
    for (int nl = 0; nl < 2; nl++) {                                                  \
      bfr[nl][0] = *(const bf16x8*)(bufB + (QN)*16384 + wno + nl*2048 + lro + colk0); \
      bfr[nl][1] = *(const bf16x8*)(bufB + (QN)*16384 + wno + nl*2048 + lro + colk1); \
    }                                                                                 \
    _Pragma("unroll")                                                                 \
    for (int i = 0; i < 2; i++) {                                                     \
      if ((SU) == 0) async16(ldsAn + o16[i],         Ag + (size_t)aRow[i]*LD + kn + aCol[i]);        \
      if ((SU) == 1) async16(ldsBn + o16[i],         Bg + (size_t)bRow[i]*LD + kn + bCol[i]);        \
      if ((SU) == 2) async16(ldsAn + 16384 + o16[i], Ag + (size_t)(aRow[i] + 64)*LD + kn + aCol[i]); \
      if ((SU) == 3) async16(ldsBn + 16384 + o16[i], Bg + (size_t)(bRow[i] + 32)*LD + kn + bCol[i]); \
    }                                                                                 \
    __builtin_amdgcn_sched_barrier(0);                                                \
    __builtin_amdgcn_s_barrier();                                                     \
    asm volatile("s_waitcnt lgkmcnt(0)" ::: "memory");                                \
    __builtin_amdgcn_sched_barrier(0);                                                \
    __builtin_amdgcn_s_setprio(1);                                                    \
    _Pragma("unroll")                                                                 \
    for (int ml = 0; ml < 4; ml++)                                                    \
      _Pragma("unroll")                                                               \
      for (int nl = 0; nl < 2; nl++) {                                                \
        acc[(QM)*4+ml][(QN)*2+nl] = __builtin_amdgcn_mfma_f32_16x16x32_bf16(          \
            afr[ml][0], bfr[nl][0], acc[(QM)*4+ml][(QN)*2+nl], 0, 0, 0);              \
        acc[(QM)*4+ml][(QN)*2+nl] = __builtin_amdgcn_mfma_f32_16x16x32_bf16(          \
            afr[ml][1], bfr[nl][1], acc[(QM)*4+ml][(QN)*2+nl], 0, 0, 0);              \
      }                                                                               \
    __builtin_amdgcn_s_setprio(0);                                                    \
    __builtin_amdgcn_sched_barrier(0);                                                \
    if (WAIT_) { asm volatile("s_waitcnt vmcnt(4)" ::: "memory"); }                   \
    __builtin_amdgcn_s_barrier();                                                     \
    __builtin_amdgcn_sched_barrier(0);                                                \
  }

// EPI: 1 = gelu*rw -> bf16 Cb;  2 = f32 -> selected Cf
// KEXT: K extent of this pass; LD: row stride of A and B; NBN: N-tiles;
// SPLITK: 1 or 2 (kz decoded from swizzled block id; kz==1 writes Cf2)
template <int EPI, int KEXT, int LD, int NBN, int SPLITK>
__global__ __launch_bounds__(512, 2)
void gemm256(const unsigned short* __restrict__ A, const unsigned short* __restrict__ B,
             float* __restrict__ Cf, float* __restrict__ Cf2,
             unsigned short* __restrict__ Cb, const float* __restrict__ rw) {
  __shared__ __align__(1024) char lds[131072];
  constexpr int NT = KEXT / 64;
  const int tid = threadIdx.x;
  const int lane = tid & 63, wid = tid >> 6;
  const int wm = wid >> 2, wn = wid & 3;
  const int lr = lane & 15;

  // bijective XCD swizzle (gridDim.x % 8 == 0 for all instantiations)
  const int nwg = gridDim.x;
  const int cpx = nwg >> 3;
  int wg = (blockIdx.x & 7) * cpx + (blockIdx.x >> 3);
  int kz = 0;
  if (SPLITK == 2) { kz = wg / (nwg >> 1); wg = wg % (nwg >> 1); }
  const int bm = wg / NBN, bn = wg % NBN;

  const int swz = (lr & 7) << 4;
  const int colk0 = ((lane >> 4) * 16) ^ swz;
  const int colk1 = (64 + (lane >> 4) * 16) ^ swz;
  const int wmo = wm * 8192, wno = wn * 4096, lro = lr * 128;

  int aRow[2], aCol[2], bRow[2], bCol[2], o16[2];
  #pragma unroll
  for (int i = 0; i < 2; i++) {
    int o = (i * 512 + tid) * 16;
    o16[i] = o;
    { int wmb = o >> 13, ob = o & 8191, r = ob >> 7, cb = ob & 127;
      aRow[i] = wmb * 128 + r; aCol[i] = (cb ^ ((r & 7) << 4)) >> 1; }
    { int wnb = o >> 12, ob = o & 4095, r = ob >> 7, cb = ob & 127;
      bRow[i] = wnb * 64 + r; bCol[i] = (cb ^ ((r & 7) << 4)) >> 1; }
  }

  const unsigned short* Ag = A + (size_t)bm * 256 * LD + (size_t)kz * KEXT;
  const unsigned short* Bg = B + (size_t)bn * 256 * LD + (size_t)kz * KEXT;

  f32x4 acc[8][4];
  #pragma unroll
  for (int m = 0; m < 8; m++)
    #pragma unroll
    for (int n = 0; n < 4; n++) acc[m][n] = (f32x4){0.f, 0.f, 0.f, 0.f};

  // prologue: stage tile 0 into buf0 (A0,B0,A1,B1), drain, barrier
  #pragma unroll
  for (int i = 0; i < 2; i++) async16(lds + o16[i],                 Ag + (size_t)aRow[i] * LD + aCol[i]);
  #pragma unroll
  for (int i = 0; i < 2; i++) async16(lds + 65536 + o16[i],         Bg + (size_t)bRow[i] * LD + bCol[i]);
  #pragma unroll
  for (int i = 0; i < 2; i++) async16(lds + 16384 + o16[i],         Ag + (size_t)(aRow[i] + 64) * LD + aCol[i]);
  #pragma unroll
  for (int i = 0; i < 2; i++) async16(lds + 65536 + 16384 + o16[i], Bg + (size_t)(bRow[i] + 32) * LD + bCol[i]);
  asm volatile("s_waitcnt vmcnt(0)" ::: "memory");
  __builtin_amdgcn_s_barrier();

  #pragma unroll 1
  for (int t = 0; t < NT; t += 2) {
    {
      const char* bufA = lds;               // cur buf0
      const char* bufB = lds + 65536;
      char* ldsAn = lds + 32768;            // stage into buf1
      char* ldsBn = lds + 65536 + 32768;
      const int kn = ((t + 1) & (NT - 1)) << 6;
      PHASE(0, 0, 0, 1)
      PHASE(1, 0, 1, 1)
      PHASE(0, 1, 2, 0)
      PHASE(1, 1, 3, 1)
    }
    {
      const char* bufA = lds + 32768;       // cur buf1
      const char* bufB = lds + 65536 + 32768;
      char* ldsAn = lds;                    // stage into buf0
      char* ldsBn = lds + 65536;
      const int kn = ((t + 2) & (NT - 1)) << 6;
      PHASE(0, 0, 0, 1)
      PHASE(1, 0, 1, 1)
      PHASE(0, 1, 2, 0)
      PHASE(1, 1, 3, 1)
    }
  }

  asm volatile("s_waitcnt vmcnt(0)" ::: "memory");

  // epilogue: C/D layout col=lane&15, row=(lane>>4)*4+j
  const int jr = (lane >> 4) * 4;
  if (EPI == 1) {
    float wrow[8][4];
    #pragma unroll
    for (int m = 0; m < 8; m++)
      #pragma unroll
      for (int j = 0; j < 4; j++)
        wrow[m][j] = rw[(size_t)(bm * 256 + wm * 128 + m * 16 + jr + j) * 16 + bn];
    #pragma unroll
    for (int m = 0; m < 8; m++) {
      #pragma unroll
      for (int n = 0; n < 4; n++) {
        int col = bn * 256 + wn * 64 + n * 16 + lr;
        #pragma unroll
        for (int j = 0; j < 4; j++) {
          int r = bm * 256 + wm * 128 + m * 16 + jr + j;
          float v = acc[m][n][j];
          float g = 0.7978845608f * (v + 0.044715f * v * v * v);
          float e = __expf(2.f * g);
          float th = 1.f - 2.f / (e + 1.f);   // tanh(g), inf-safe
          float ge = 0.5f * v * (1.f + th);
          Cb[(size_t)r * NBIG + col] = f2bf(ge * wrow[m][j]);
        }
      }
    }
  } else {
    float* cfp = (SPLITK == 2 && kz == 1) ? Cf2 : Cf;
    #pragma unroll
    for (int m = 0; m < 8; m++) {
      #pragma unroll
      for (int n = 0; n < 4; n++) {
        int col = bn * 256 + wn * 64 + n * 16 + lr;
        #pragma unroll
        for (int j = 0; j < 4; j++) {
          int r = bm * 256 + wm * 128 + m * 16 + jr + j;
          cfp[(size_t)r * HID + col] = acc[m][n][j];
        }
      }
    }
  }
}

// ---------------- out += p1 (f32x4, grid-stride) ----------------
__global__ __launch_bounds__(256)
void addk(float* __restrict__ out, const float* __restrict__ p1, int n4) {
  int i = blockIdx.x * blockDim.x + threadIdx.x;
  const int stride = gridDim.x * blockDim.x;
  for (; i < n4; i += stride) {
    float4 a = ((const float4*)out)[i];
    float4 b = ((const float4*)p1)[i];
    a.x += b.x; a.y += b.y; a.z += b.z; a.w += b.w;
    ((float4*)out)[i] = a;
  }
}

extern "C" void kernel_launch(void* const* d_in, const int* in_sizes, int n_in,
                              void* d_out, int out_size, void* d_ws, size_t ws_size,
                              hipStream_t stream) {
  const float* x   = (const float*)d_in[0];
  const float* sm  = (const float*)d_in[1];
  const float* thr = (const float*)d_in[2];
  const float* w1  = (const float*)d_in[3];
  const float* w2  = (const float*)d_in[4];

  float* out_final  = (float*)d_out;
  float* out_scores = out_final + (size_t)NTOK * HID;
  float* out_k      = out_scores + (size_t)NTOK * NEXP;

  char* ws = (char*)d_ws;
  size_t off = 0;
  float* inv_smn = (float*)(ws + off); off += 256;
  float* rwbuf   = (float*)(ws + off); off += (size_t)NTOK * NEXP * 4;        // 512 KiB
  unsigned short* Xb  = (unsigned short*)(ws + off); off += (size_t)NTOK * HID * 2;   // 16 MiB
  unsigned short* W1T = (unsigned short*)(ws + off); off += (size_t)NBIG * HID * 2;   // 8 MiB
  unsigned short* W2T = (unsigned short*)(ws + off); off += (size_t)HID * NBIG * 2;   // 8 MiB
  unsigned short* H   = (unsigned short*)(ws + off); off += (size_t)NTOK * NBIG * 2;  // 64 MiB
  float* P1 = (float*)(ws + off);
  const bool split = ws_size >= off + (size_t)NTOK * HID * 4;                 // +32 MiB

  simnorm_kernel<<<1, 256, 0, stream>>>(sm, inv_smn);
  gate_kernel<<<NTOK, 256, 0, stream>>>(x, sm, thr, inv_smn, out_scores, out_k, rwbuf, Xb);
  transpose_cast_kernel<<<dim3(ISZ / 32, HID / 32, NEXP), 256, 0, stream>>>(
      w1, W1T, HID, ISZ, HID, HID * ISZ, ISZ * HID);
  transpose_cast_kernel<<<dim3(HID / 32, ISZ / 32, NEXP), 256, 0, stream>>>(
      w2, W2T, ISZ, HID, NBIG, ISZ * HID, ISZ);

  // H = gelu(Xb @ W1T^T) * rw   [8192 x 4096], 512 blocks
  gemm256<1, HID, HID, 16, 1><<<512, 512, 0, stream>>>(Xb, W1T, nullptr, nullptr, H, rwbuf);

  if (split) {
    // final = H @ W2T^T via split-K=2: 256 blocks (full machine), then add
    gemm256<2, NBIG / 2, NBIG, 4, 2><<<256, 512, 0, stream>>>(H, W2T, out_final, P1, nullptr, nullptr);
    addk<<<2048, 256, 0, stream>>>(out_final, P1, NTOK * HID / 4);
  } else {
    // fallback: verified single-pass, 128 blocks
    gemm256<2, NBIG, NBIG, 4, 1><<<128, 512, 0, stream>>>(H, W2T, out_final, nullptr, nullptr, nullptr);
  }
}

// Round 5
// 236.024 us; speedup vs baseline: 1.2719x; 1.0273x over previous
//
#include <hip/hip_runtime.h>
#include <hip/hip_bf16.h>
#include <math.h>

#define NTOK 8192
#define HID  1024
#define ISZ  256
#define NEXP 16
#define NBIG 4096  // NEXP*ISZ

typedef __attribute__((ext_vector_type(8))) short bf16x8;
typedef __attribute__((ext_vector_type(4))) float f32x4;

__device__ __forceinline__ unsigned short f2bf(float f) {
  unsigned u = __float_as_uint(f);
  u += 0x7fff + ((u >> 16) & 1);
  return (unsigned short)(u >> 16);
}

__device__ __forceinline__ void async16(void* l, const void* g) {
  __builtin_amdgcn_global_load_lds(
      (const __attribute__((address_space(1))) unsigned int*)g,
      (__attribute__((address_space(3))) unsigned int*)l, 16, 0, 0);
}

// ---------------- sim_matrix column inverse norms ----------------
__global__ void simnorm_kernel(const float* __restrict__ sm, float* __restrict__ inv_smn) {
  __shared__ float red[16][17];
  int t = threadIdx.x;
  int e = t & 15, g = t >> 4;
  float ss = 0.f;
  for (int c = g; c < HID; c += 16) {
    float v = sm[c * NEXP + e];
    ss += v * v;
  }
  red[e][g] = ss;
  __syncthreads();
  if (t < 16) {
    float s = 0.f;
    #pragma unroll
    for (int i = 0; i < 16; i++) s += red[t][i];
    inv_smn[t] = 1.f / fmaxf(sqrtf(s), 1e-12f);
  }
}

// ---------------- gate: scores, k, routing weights, bf16 cast of x ----------------
__global__ __launch_bounds__(256)
void gate_kernel(const float* __restrict__ x, const float* __restrict__ sm,
                 const float* __restrict__ thr, const float* __restrict__ inv_smn,
                 float* __restrict__ scores_out, float* __restrict__ k_out,
                 float* __restrict__ rw_out, unsigned short* __restrict__ xb_out) {
  const int n = blockIdx.x;
  const int t = threadIdx.x;
  const int lane = t & 63, wave = t >> 6;
  const float* xr = x + (size_t)n * HID;

  float p[16];
  #pragma unroll
  for (int e = 0; e < 16; e++) p[e] = 0.f;
  float ss = 0.f;

  #pragma unroll
  for (int q = 0; q < 4; q++) {
    int c = t + q * 256;
    float v = xr[c];
    ss += v * v;
    xb_out[(size_t)n * HID + c] = f2bf(v);
    const float4* smr = (const float4*)(sm + (size_t)c * NEXP);
    float4 s0 = smr[0], s1 = smr[1], s2 = smr[2], s3 = smr[3];
    p[0] += v * s0.x;  p[1] += v * s0.y;  p[2] += v * s0.z;  p[3] += v * s0.w;
    p[4] += v * s1.x;  p[5] += v * s1.y;  p[6] += v * s1.z;  p[7] += v * s1.w;
    p[8] += v * s2.x;  p[9] += v * s2.y;  p[10] += v * s2.z; p[11] += v * s2.w;
    p[12] += v * s3.x; p[13] += v * s3.y; p[14] += v * s3.z; p[15] += v * s3.w;
  }

  #pragma unroll
  for (int off = 32; off > 0; off >>= 1) {
    ss += __shfl_down(ss, off, 64);
    #pragma unroll
    for (int e = 0; e < 16; e++) p[e] += __shfl_down(p[e], off, 64);
  }

  __shared__ float red[4][17];
  __shared__ float sc[16];
  if (lane == 0) {
    red[wave][0] = ss;
    #pragma unroll
    for (int e = 0; e < 16; e++) red[wave][1 + e] = p[e];
  }
  __syncthreads();

  if (t < 16) {
    float d = red[0][1 + t] + red[1][1 + t] + red[2][1 + t] + red[3][1 + t];
    float ssum = red[0][0] + red[1][0] + red[2][0] + red[3][0];
    float inv_x = 1.f / fmaxf(sqrtf(ssum), 1e-12f);
    float s = d * inv_x * inv_smn[t];
    scores_out[(size_t)n * 16 + t] = s;
    sc[t] = s;
  }
  __syncthreads();

  if (t < 16) {
    float thrv = thr[0];
    float s = sc[t];
    bool act = s > thrv;
    float m = act ? s : -INFINITY;
    int cnt = act ? 1 : 0;
    #pragma unroll
    for (int off = 8; off > 0; off >>= 1) {
      m = fmaxf(m, __shfl_xor(m, off, 16));
      cnt += __shfl_xor(cnt, off, 16);
    }
    float pv;
    if (cnt > 0) pv = act ? expf(s - m) : 0.f;
    else         pv = 1.f;
    float sum = pv;
    #pragma unroll
    for (int off = 8; off > 0; off >>= 1) sum += __shfl_xor(sum, off, 16);
    rw_out[(size_t)n * 16 + t] = pv / sum;
    if (t == 0) k_out[n] = (float)cnt;
  }
}

// ---------------- transpose + bf16 cast (per-expert 2D transpose) ----------------
__global__ __launch_bounds__(256)
void transpose_cast_kernel(const float* __restrict__ src, unsigned short* __restrict__ dst,
                           int R, int C, int dstride, int e_src_stride, int e_dst_mult) {
  __shared__ float tile[32][33];
  const int e = blockIdx.z;
  const int r0 = blockIdx.y * 32, c0 = blockIdx.x * 32;
  const int tx = threadIdx.x & 31, ty = threadIdx.x >> 5;
  const float* s = src + (size_t)e * e_src_stride;
  #pragma unroll
  for (int q = 0; q < 4; q++) {
    int r = r0 + ty + q * 8;
    tile[ty + q * 8][tx] = s[(size_t)r * C + c0 + tx];
  }
  __syncthreads();
  unsigned short* d = dst + (size_t)e * e_dst_mult;
  #pragma unroll
  for (int q = 0; q < 4; q++) {
    int cc = c0 + ty + q * 8;
    int r  = r0 + tx;
    d[(size_t)cc * dstride + r] = f2bf(tile[tx][ty + q * 8]);
  }
}

// ================= 256x256 8-wave 4-phase pipelined MFMA GEMM =================
// r2-verified barrier skeleton; phases re-shaped to (m-half Q x kk-half CK):
// each phase: 4 A-frag + 4 B-frag ds_read_b128 (8 total, was 12), 16 MFMA.
// Per K-tile: A read once, B twice -> 32 reads (was 48).
// Stage order per K-tile: A0@P0, B0@P1, B1@P2, A1@P3.
// Waits: P0 vmcnt(4) [no-op], P1 vmcnt(4) [retires A1(t) before P2 use],
// P2 none, P3 vmcnt(2) [retires A0,B0,B1(t+1) before next P0]. Max 8 in flight.
#define PHASE(Q, CK, SU, WAIT_)                                                       \
  {                                                                                   \
    bf16x8 afr[4], bfr[4];                                                            \
    _Pragma("unroll")                                                                 \
    for (int fm = 0; fm < 4; fm++)                                                    \
      afr[fm] = *(const bf16x8*)(bufA + (Q)*16384 + wmo + fm*2048 + lro + (CK));      \
    _Pragma("unroll")                                                                 \
    for (int fn = 0; fn < 2; fn++) {                                                  \
      bfr[fn]     = *(const bf16x8*)(bufB + wno + fn*2048 + lro + (CK));              \
      bfr[2 + fn] = *(const bf16x8*)(bufB + 16384 + wno + fn*2048 + lro + (CK));      \
    }                                                                                 \
    _Pragma("unroll")                                                                 \
    for (int i = 0; i < 2; i++) {                                                     \
      if ((SU) == 0) async16(ldsAn + o16[i],         Ag + (size_t)aRow[i]*LD + kn + aCol[i]);        \
      if ((SU) == 1) async16(ldsBn + o16[i],         Bg + (size_t)bRow[i]*LD + kn + bCol[i]);        \
      if ((SU) == 2) async16(ldsAn + 16384 + o16[i], Ag + (size_t)(aRow[i] + 64)*LD + kn + aCol[i]); \
      if ((SU) == 3) async16(ldsBn + 16384 + o16[i], Bg + (size_t)(bRow[i] + 32)*LD + kn + bCol[i]); \
    }                                                                                 \
    __builtin_amdgcn_sched_barrier(0);                                                \
    __builtin_amdgcn_s_barrier();                                                     \
    asm volatile("s_waitcnt lgkmcnt(0)" ::: "memory");                                \
    __builtin_amdgcn_sched_barrier(0);                                                \
    __builtin_amdgcn_s_setprio(1);                                                    \
    _Pragma("unroll")                                                                 \
    for (int fm = 0; fm < 4; fm++)                                                    \
      _Pragma("unroll")                                                               \
      for (int fn = 0; fn < 4; fn++)                                                  \
        acc[(Q)*4+fm][fn] = __builtin_amdgcn_mfma_f32_16x16x32_bf16(                  \
            afr[fm], bfr[fn], acc[(Q)*4+fm][fn], 0, 0, 0);                            \
    __builtin_amdgcn_s_setprio(0);                                                    \
    __builtin_amdgcn_sched_barrier(0);                                                \
    if ((WAIT_) == 4) { asm volatile("s_waitcnt vmcnt(4)" ::: "memory"); }            \
    if ((WAIT_) == 2) { asm volatile("s_waitcnt vmcnt(2)" ::: "memory"); }            \
    __builtin_amdgcn_s_barrier();                                                     \
    __builtin_amdgcn_sched_barrier(0);                                                \
  }

// EPI: 1 = gelu*rw -> bf16 Cb;  2 = f32 -> selected Cf
template <int EPI, int KEXT, int LD, int NBN, int SPLITK>
__global__ __launch_bounds__(512, 2)
void gemm256(const unsigned short* __restrict__ A, const unsigned short* __restrict__ B,
             float* __restrict__ Cf, float* __restrict__ Cf2,
             unsigned short* __restrict__ Cb, const float* __restrict__ rw) {
  __shared__ __align__(1024) char lds[131072];
  constexpr int NT = KEXT / 64;
  const int tid = threadIdx.x;
  const int lane = tid & 63, wid = tid >> 6;
  const int wm = wid >> 2, wn = wid & 3;
  const int lr = lane & 15;

  // bijective XCD swizzle (gridDim.x % 8 == 0 for all instantiations)
  const int nwg = gridDim.x;
  const int cpx = nwg >> 3;
  int wg = (blockIdx.x & 7) * cpx + (blockIdx.x >> 3);
  int kz = 0;
  if (SPLITK == 2) { kz = wg / (nwg >> 1); wg = wg % (nwg >> 1); }
  const int bm = wg / NBN, bn = wg % NBN;

  const int swz = (lr & 7) << 4;
  const int colk0 = ((lane >> 4) * 16) ^ swz;
  const int colk1 = (64 + (lane >> 4) * 16) ^ swz;
  const int wmo = wm * 8192, wno = wn * 4096, lro = lr * 128;

  int aRow[2], aCol[2], bRow[2], bCol[2], o16[2];
  #pragma unroll
  for (int i = 0; i < 2; i++) {
    int o = (i * 512 + tid) * 16;
    o16[i] = o;
    { int wmb = o >> 13, ob = o & 8191, r = ob >> 7, cb = ob & 127;
      aRow[i] = wmb * 128 + r; aCol[i] = (cb ^ ((r & 7) << 4)) >> 1; }
    { int wnb = o >> 12, ob = o & 4095, r = ob >> 7, cb = ob & 127;
      bRow[i] = wnb * 64 + r; bCol[i] = (cb ^ ((r & 7) << 4)) >> 1; }
  }

  const unsigned short* Ag = A + (size_t)bm * 256 * LD + (size_t)kz * KEXT;
  const unsigned short* Bg = B + (size_t)bn * 256 * LD + (size_t)kz * KEXT;

  f32x4 acc[8][4];
  #pragma unroll
  for (int m = 0; m < 8; m++)
    #pragma unroll
    for (int n = 0; n < 4; n++) acc[m][n] = (f32x4){0.f, 0.f, 0.f, 0.f};

  // prologue: stage tile 0 into buf0, order A0,B0,B1,A1; vmcnt(2) leaves A1 in
  // flight (retired by P1's vmcnt(4), matching steady state)
  #pragma unroll
  for (int i = 0; i < 2; i++) async16(lds + o16[i],                 Ag + (size_t)aRow[i] * LD + aCol[i]);
  #pragma unroll
  for (int i = 0; i < 2; i++) async16(lds + 65536 + o16[i],         Bg + (size_t)bRow[i] * LD + bCol[i]);
  #pragma unroll
  for (int i = 0; i < 2; i++) async16(lds + 65536 + 16384 + o16[i], Bg + (size_t)(bRow[i] + 32) * LD + bCol[i]);
  #pragma unroll
  for (int i = 0; i < 2; i++) async16(lds + 16384 + o16[i],         Ag + (size_t)(aRow[i] + 64) * LD + aCol[i]);
  asm volatile("s_waitcnt vmcnt(2)" ::: "memory");
  __builtin_amdgcn_s_barrier();

  #pragma unroll 1
  for (int t = 0; t < NT; t += 2) {
    {
      const char* bufA = lds;               // cur buf0
      const char* bufB = lds + 65536;
      char* ldsAn = lds + 32768;            // stage into buf1
      char* ldsBn = lds + 65536 + 32768;
      const int kn = ((t + 1) & (NT - 1)) << 6;
      PHASE(0, colk0, 0, 4)
      PHASE(0, colk1, 1, 4)
      PHASE(1, colk0, 3, 0)
      PHASE(1, colk1, 2, 2)
    }
    {
      const char* bufA = lds + 32768;       // cur buf1
      const char* bufB = lds + 65536 + 32768;
      char* ldsAn = lds;                    // stage into buf0
      char* ldsBn = lds + 65536;
      const int kn = ((t + 2) & (NT - 1)) << 6;
      PHASE(0, colk0, 0, 4)
      PHASE(0, colk1, 1, 4)
      PHASE(1, colk0, 3, 0)
      PHASE(1, colk1, 2, 2)
    }
  }

  asm volatile("s_waitcnt vmcnt(0)" ::: "memory");

  // epilogue: C/D layout col=lane&15, row=(lane>>4)*4+j
  const int jr = (lane >> 4) * 4;
  if (EPI == 1) {
    float wrow[8][4];
    #pragma unroll
    for (int m = 0; m < 8; m++)
      #pragma unroll
      for (int j = 0; j < 4; j++)
        wrow[m][j] = rw[(size_t)(bm * 256 + wm * 128 + m * 16 + jr + j) * 16 + bn];
    #pragma unroll
    for (int m = 0; m < 8; m++) {
      #pragma unroll
      for (int n = 0; n < 4; n++) {
        int col = bn * 256 + wn * 64 + n * 16 + lr;
        #pragma unroll
        for (int j = 0; j < 4; j++) {
          int r = bm * 256 + wm * 128 + m * 16 + jr + j;
          float v = acc[m][n][j];
          float g = 0.7978845608f * (v + 0.044715f * v * v * v);
          float e = __expf(2.f * g);
          float th = 1.f - 2.f / (e + 1.f);   // tanh(g), inf-safe
          float ge = 0.5f * v * (1.f + th);
          Cb[(size_t)r * NBIG + col] = f2bf(ge * wrow[m][j]);
        }
      }
    }
  } else {
    float* cfp = (SPLITK == 2 && kz == 1) ? Cf2 : Cf;
    #pragma unroll
    for (int m = 0; m < 8; m++) {
      #pragma unroll
      for (int n = 0; n < 4; n++) {
        int col = bn * 256 + wn * 64 + n * 16 + lr;
        #pragma unroll
        for (int j = 0; j < 4; j++) {
          int r = bm * 256 + wm * 128 + m * 16 + jr + j;
          cfp[(size_t)r * HID + col] = acc[m][n][j];
        }
      }
    }
  }
}

// ---------------- out += p1 (f32x4, grid-stride) ----------------
__global__ __launch_bounds__(256)
void addk(float* __restrict__ out, const float* __restrict__ p1, int n4) {
  int i = blockIdx.x * blockDim.x + threadIdx.x;
  const int stride = gridDim.x * blockDim.x;
  for (; i < n4; i += stride) {
    float4 a = ((const float4*)out)[i];
    float4 b = ((const float4*)p1)[i];
    a.x += b.x; a.y += b.y; a.z += b.z; a.w += b.w;
    ((float4*)out)[i] = a;
  }
}

extern "C" void kernel_launch(void* const* d_in, const int* in_sizes, int n_in,
                              void* d_out, int out_size, void* d_ws, size_t ws_size,
                              hipStream_t stream) {
  const float* x   = (const float*)d_in[0];
  const float* sm  = (const float*)d_in[1];
  const float* thr = (const float*)d_in[2];
  const float* w1  = (const float*)d_in[3];
  const float* w2  = (const float*)d_in[4];

  float* out_final  = (float*)d_out;
  float* out_scores = out_final + (size_t)NTOK * HID;
  float* out_k      = out_scores + (size_t)NTOK * NEXP;

  char* ws = (char*)d_ws;
  size_t off = 0;
  float* inv_smn = (float*)(ws + off); off += 256;
  float* rwbuf   = (float*)(ws + off); off += (size_t)NTOK * NEXP * 4;        // 512 KiB
  unsigned short* Xb  = (unsigned short*)(ws + off); off += (size_t)NTOK * HID * 2;   // 16 MiB
  unsigned short* W1T = (unsigned short*)(ws + off); off += (size_t)NBIG * HID * 2;   // 8 MiB
  unsigned short* W2T = (unsigned short*)(ws + off); off += (size_t)HID * NBIG * 2;   // 8 MiB
  unsigned short* H   = (unsigned short*)(ws + off); off += (size_t)NTOK * NBIG * 2;  // 64 MiB
  float* P1 = (float*)(ws + off);
  const bool split = ws_size >= off + (size_t)NTOK * HID * 4;                 // +32 MiB

  simnorm_kernel<<<1, 256, 0, stream>>>(sm, inv_smn);
  gate_kernel<<<NTOK, 256, 0, stream>>>(x, sm, thr, inv_smn, out_scores, out_k, rwbuf, Xb);
  transpose_cast_kernel<<<dim3(ISZ / 32, HID / 32, NEXP), 256, 0, stream>>>(
      w1, W1T, HID, ISZ, HID, HID * ISZ, ISZ * HID);
  transpose_cast_kernel<<<dim3(HID / 32, ISZ / 32, NEXP), 256, 0, stream>>>(
      w2, W2T, ISZ, HID, NBIG, ISZ * HID, ISZ);

  // H = gelu(Xb @ W1T^T) * rw   [8192 x 4096], 512 blocks
  gemm256<1, HID, HID, 16, 1><<<512, 512, 0, stream>>>(Xb, W1T, nullptr, nullptr, H, rwbuf);

  if (split) {
    // final = H @ W2T^T via split-K=2: 256 blocks (full machine), then add
    gemm256<2, NBIG / 2, NBIG, 4, 2><<<256, 512, 0, stream>>>(H, W2T, out_final, P1, nullptr, nullptr);
    addk<<<2048, 256, 0, stream>>>(out_final, P1, NTOK * HID / 4);
  } else {
    // fallback: verified single-pass, 128 blocks
    gemm256<2, NBIG, NBIG, 4, 1><<<128, 512, 0, stream>>>(H, W2T, out_final, nullptr, nullptr, nullptr);
  }
}

// Round 6
// 220.961 us; speedup vs baseline: 1.3586x; 1.0682x over previous
//
#include <hip/hip_runtime.h>
#include <hip/hip_bf16.h>
#include <math.h>

#define NTOK 8192
#define HID  1024
#define ISZ  256
#define NEXP 16
#define NBIG 4096  // NEXP*ISZ

typedef __attribute__((ext_vector_type(8))) short bf16x8;
typedef __attribute__((ext_vector_type(4))) float f32x4;

__device__ __forceinline__ unsigned short f2bf(float f) {
  unsigned u = __float_as_uint(f);
  u += 0x7fff + ((u >> 16) & 1);
  return (unsigned short)(u >> 16);
}

__device__ __forceinline__ void async16(void* l, const void* g) {
  __builtin_amdgcn_global_load_lds(
      (const __attribute__((address_space(1))) unsigned int*)g,
      (__attribute__((address_space(3))) unsigned int*)l, 16, 0, 0);
}

// ---------------- sim_matrix column inverse norms ----------------
__global__ void simnorm_kernel(const float* __restrict__ sm, float* __restrict__ inv_smn) {
  __shared__ float red[16][17];
  int t = threadIdx.x;
  int e = t & 15, g = t >> 4;
  float ss = 0.f;
  for (int c = g; c < HID; c += 16) {
    float v = sm[c * NEXP + e];
    ss += v * v;
  }
  red[e][g] = ss;
  __syncthreads();
  if (t < 16) {
    float s = 0.f;
    #pragma unroll
    for (int i = 0; i < 16; i++) s += red[t][i];
    inv_smn[t] = 1.f / fmaxf(sqrtf(s), 1e-12f);
  }
}

// ---------------- gate: scores, k, routing weights, bf16 cast of x ----------------
__global__ __launch_bounds__(256)
void gate_kernel(const float* __restrict__ x, const float* __restrict__ sm,
                 const float* __restrict__ thr, const float* __restrict__ inv_smn,
                 float* __restrict__ scores_out, float* __restrict__ k_out,
                 float* __restrict__ rw_out, unsigned short* __restrict__ xb_out) {
  const int n = blockIdx.x;
  const int t = threadIdx.x;
  const int lane = t & 63, wave = t >> 6;
  const float* xr = x + (size_t)n * HID;

  float p[16];
  #pragma unroll
  for (int e = 0; e < 16; e++) p[e] = 0.f;
  float ss = 0.f;

  #pragma unroll
  for (int q = 0; q < 4; q++) {
    int c = t + q * 256;
    float v = xr[c];
    ss += v * v;
    xb_out[(size_t)n * HID + c] = f2bf(v);
    const float4* smr = (const float4*)(sm + (size_t)c * NEXP);
    float4 s0 = smr[0], s1 = smr[1], s2 = smr[2], s3 = smr[3];
    p[0] += v * s0.x;  p[1] += v * s0.y;  p[2] += v * s0.z;  p[3] += v * s0.w;
    p[4] += v * s1.x;  p[5] += v * s1.y;  p[6] += v * s1.z;  p[7] += v * s1.w;
    p[8] += v * s2.x;  p[9] += v * s2.y;  p[10] += v * s2.z; p[11] += v * s2.w;
    p[12] += v * s3.x; p[13] += v * s3.y; p[14] += v * s3.z; p[15] += v * s3.w;
  }

  #pragma unroll
  for (int off = 32; off > 0; off >>= 1) {
    ss += __shfl_down(ss, off, 64);
    #pragma unroll
    for (int e = 0; e < 16; e++) p[e] += __shfl_down(p[e], off, 64);
  }

  __shared__ float red[4][17];
  __shared__ float sc[16];
  if (lane == 0) {
    red[wave][0] = ss;
    #pragma unroll
    for (int e = 0; e < 16; e++) red[wave][1 + e] = p[e];
  }
  __syncthreads();

  if (t < 16) {
    float d = red[0][1 + t] + red[1][1 + t] + red[2][1 + t] + red[3][1 + t];
    float ssum = red[0][0] + red[1][0] + red[2][0] + red[3][0];
    float inv_x = 1.f / fmaxf(sqrtf(ssum), 1e-12f);
    float s = d * inv_x * inv_smn[t];
    scores_out[(size_t)n * 16 + t] = s;
    sc[t] = s;
  }
  __syncthreads();

  if (t < 16) {
    float thrv = thr[0];
    float s = sc[t];
    bool act = s > thrv;
    float m = act ? s : -INFINITY;
    int cnt = act ? 1 : 0;
    #pragma unroll
    for (int off = 8; off > 0; off >>= 1) {
      m = fmaxf(m, __shfl_xor(m, off, 16));
      cnt += __shfl_xor(cnt, off, 16);
    }
    float pv;
    if (cnt > 0) pv = act ? expf(s - m) : 0.f;
    else         pv = 1.f;
    float sum = pv;
    #pragma unroll
    for (int off = 8; off > 0; off >>= 1) sum += __shfl_xor(sum, off, 16);
    rw_out[(size_t)n * 16 + t] = pv / sum;
    if (t == 0) k_out[n] = (float)cnt;
  }
}

// ---------------- transpose + bf16 cast (per-expert 2D transpose) ----------------
__global__ __launch_bounds__(256)
void transpose_cast_kernel(const float* __restrict__ src, unsigned short* __restrict__ dst,
                           int R, int C, int dstride, int e_src_stride, int e_dst_mult) {
  __shared__ float tile[32][33];
  const int e = blockIdx.z;
  const int r0 = blockIdx.y * 32, c0 = blockIdx.x * 32;
  const int tx = threadIdx.x & 31, ty = threadIdx.x >> 5;
  const float* s = src + (size_t)e * e_src_stride;
  #pragma unroll
  for (int q = 0; q < 4; q++) {
    int r = r0 + ty + q * 8;
    tile[ty + q * 8][tx] = s[(size_t)r * C + c0 + tx];
  }
  __syncthreads();
  unsigned short* d = dst + (size_t)e * e_dst_mult;
  #pragma unroll
  for (int q = 0; q < 4; q++) {
    int cc = c0 + ty + q * 8;
    int r  = r0 + tx;
    d[(size_t)cc * dstride + r] = f2bf(tile[tx][ty + q * 8]);
  }
}

// ================= GEMM1: 256x256, 8-wave, 2-phase/K-tile =================
// r4/r5-verified barrier skeleton. Phase = 12 ds_read_b128 (all frags at one
// kk) + 32 MFMA. P0 stages all 4 next-tile units (8 loads); P1 ends with
// vmcnt(0) — issue-to-wait distance ~2 phases >> HBM latency.
#define G1PHASE(CK, STG, WAIT_)                                                \
  {                                                                            \
    bf16x8 afr[8], bfr[4];                                                     \
    _Pragma("unroll")                                                          \
    for (int q = 0; q < 2; q++)                                                \
      _Pragma("unroll")                                                        \
      for (int ml = 0; ml < 4; ml++)                                           \
        afr[q*4+ml] = *(const bf16x8*)(bufA + q*16384 + wmo + ml*2048 + lro + (CK)); \
    _Pragma("unroll")                                                          \
    for (int qn = 0; qn < 2; qn++)                                             \
      _Pragma("unroll")                                                        \
      for (int nl = 0; nl < 2; nl++)                                           \
        bfr[qn*2+nl] = *(const bf16x8*)(bufB + qn*16384 + wno + nl*2048 + lro + (CK)); \
    if (STG) {                                                                 \
      _Pragma("unroll")                                                        \
      for (int i = 0; i < 2; i++) {                                            \
        async16(ldsAn + o16[i],         Ag + (size_t)aRow[i]*LD + kn + aCol[i]);      \
        async16(ldsBn + o16[i],         Bg + (size_t)bRow[i]*LD + kn + bCol[i]);      \
        async16(ldsBn + 16384 + o16[i], Bg + (size_t)(bRow[i]+32)*LD + kn + bCol[i]); \
        async16(ldsAn + 16384 + o16[i], Ag + (size_t)(aRow[i]+64)*LD + kn + aCol[i]); \
      }                                                                        \
    }                                                                          \
    __builtin_amdgcn_sched_barrier(0);                                         \
    __builtin_amdgcn_s_barrier();                                              \
    asm volatile("s_waitcnt lgkmcnt(0)" ::: "memory");                         \
    __builtin_amdgcn_sched_barrier(0);                                         \
    __builtin_amdgcn_s_setprio(1);                                             \
    _Pragma("unroll")                                                          \
    for (int m8 = 0; m8 < 8; m8++)                                             \
      _Pragma("unroll")                                                        \
      for (int n4 = 0; n4 < 4; n4++)                                           \
        acc[m8][n4] = __builtin_amdgcn_mfma_f32_16x16x32_bf16(                 \
            afr[m8], bfr[n4], acc[m8][n4], 0, 0, 0);                           \
    __builtin_amdgcn_s_setprio(0);                                             \
    __builtin_amdgcn_sched_barrier(0);                                         \
    if (WAIT_) { asm volatile("s_waitcnt vmcnt(0)" ::: "memory"); }            \
    __builtin_amdgcn_s_barrier();                                              \
    __builtin_amdgcn_sched_barrier(0);                                         \
  }

template <int KEXT, int LD, int NBN>
__global__ __launch_bounds__(512, 2)
void gemm1_k(const unsigned short* __restrict__ A, const unsigned short* __restrict__ B,
             unsigned short* __restrict__ Cb, const float* __restrict__ rw) {
  __shared__ __align__(1024) char lds[131072];
  constexpr int NT = KEXT / 64;
  const int tid = threadIdx.x;
  const int lane = tid & 63, wid = tid >> 6;
  const int wm = wid >> 2, wn = wid & 3;
  const int lr = lane & 15;

  const int nwg = gridDim.x;
  const int cpx = nwg >> 3;
  int wg = (blockIdx.x & 7) * cpx + (blockIdx.x >> 3);
  const int bm = wg / NBN, bn = wg % NBN;

  const int swz = (lr & 7) << 4;
  const int colk0 = ((lane >> 4) * 16) ^ swz;
  const int colk1 = (64 + (lane >> 4) * 16) ^ swz;
  const int wmo = wm * 8192, wno = wn * 4096, lro = lr * 128;

  int aRow[2], aCol[2], bRow[2], bCol[2], o16[2];
  #pragma unroll
  for (int i = 0; i < 2; i++) {
    int o = (i * 512 + tid) * 16;
    o16[i] = o;
    { int wmb = o >> 13, ob = o & 8191, r = ob >> 7, cb = ob & 127;
      aRow[i] = wmb * 128 + r; aCol[i] = (cb ^ ((r & 7) << 4)) >> 1; }
    { int wnb = o >> 12, ob = o & 4095, r = ob >> 7, cb = ob & 127;
      bRow[i] = wnb * 64 + r; bCol[i] = (cb ^ ((r & 7) << 4)) >> 1; }
  }

  const unsigned short* Ag = A + (size_t)bm * 256 * LD;
  const unsigned short* Bg = B + (size_t)bn * 256 * LD;

  f32x4 acc[8][4];
  #pragma unroll
  for (int m = 0; m < 8; m++)
    #pragma unroll
    for (int n = 0; n < 4; n++) acc[m][n] = (f32x4){0.f, 0.f, 0.f, 0.f};

  // prologue: stage tile 0 into buf0, drain, barrier
  #pragma unroll
  for (int i = 0; i < 2; i++) async16(lds + o16[i],                 Ag + (size_t)aRow[i] * LD + aCol[i]);
  #pragma unroll
  for (int i = 0; i < 2; i++) async16(lds + 65536 + o16[i],         Bg + (size_t)bRow[i] * LD + bCol[i]);
  #pragma unroll
  for (int i = 0; i < 2; i++) async16(lds + 65536 + 16384 + o16[i], Bg + (size_t)(bRow[i] + 32) * LD + bCol[i]);
  #pragma unroll
  for (int i = 0; i < 2; i++) async16(lds + 16384 + o16[i],         Ag + (size_t)(aRow[i] + 64) * LD + aCol[i]);
  asm volatile("s_waitcnt vmcnt(0)" ::: "memory");
  __builtin_amdgcn_s_barrier();

  #pragma unroll 1
  for (int t = 0; t < NT; t += 2) {
    {
      const char* bufA = lds;               // cur buf0
      const char* bufB = lds + 65536;
      char* ldsAn = lds + 32768;            // stage into buf1
      char* ldsBn = lds + 65536 + 32768;
      const int kn = ((t + 1) & (NT - 1)) << 6;
      G1PHASE(colk0, 1, 0)
      G1PHASE(colk1, 0, 1)
    }
    {
      const char* bufA = lds + 32768;       // cur buf1
      const char* bufB = lds + 65536 + 32768;
      char* ldsAn = lds;                    // stage into buf0
      char* ldsBn = lds + 65536;
      const int kn = ((t + 2) & (NT - 1)) << 6;
      G1PHASE(colk0, 1, 0)
      G1PHASE(colk1, 0, 1)
    }
  }

  asm volatile("s_waitcnt vmcnt(0)" ::: "memory");

  // epilogue: C/D layout col=lane&15, row=(lane>>4)*4+j
  const int jr = (lane >> 4) * 4;
  float wrow[8][4];
  #pragma unroll
  for (int m = 0; m < 8; m++)
    #pragma unroll
    for (int j = 0; j < 4; j++)
      wrow[m][j] = rw[(size_t)(bm * 256 + wm * 128 + m * 16 + jr + j) * 16 + bn];
  #pragma unroll
  for (int m = 0; m < 8; m++) {
    #pragma unroll
    for (int n = 0; n < 4; n++) {
      int col = bn * 256 + wn * 64 + n * 16 + lr;
      #pragma unroll
      for (int j = 0; j < 4; j++) {
        int r = bm * 256 + wm * 128 + m * 16 + jr + j;
        float v = acc[m][n][j];
        float g = 0.7978845608f * (v + 0.044715f * v * v * v);
        float e = __expf(2.f * g);
        float th = 1.f - 2.f / (e + 1.f);   // tanh(g), inf-safe
        float ge = 0.5f * v * (1.f + th);
        Cb[(size_t)r * NBIG + col] = f2bf(ge * wrow[m][j]);
      }
    }
  }
}

// ============ GEMM2: 128x256, 8-wave (2x4), 2-phase/K-tile, K=4096 ============
// Same barrier skeleton. LDS 96 KiB: A dbuf 2x16KB @0, B dbuf 2x32KB @32768.
// A tile [128 r][128 B], B tile [256 r][128 B], swizzle byte^=(r&7)<<4 via
// pre-swizzled global source (linear DMA dest) + same XOR on reads.
// Phase = 8 ds_read_b128 + 16 MFMA. P0 stages 6 units; P1 vmcnt(0).
#define G2PHASE(CK, STG, WAIT_)                                                \
  {                                                                            \
    bf16x8 afr[4], bfr[4];                                                     \
    _Pragma("unroll")                                                          \
    for (int ml = 0; ml < 4; ml++)                                             \
      afr[ml] = *(const bf16x8*)(bufA + wmo + ml*2048 + lro + (CK));           \
    _Pragma("unroll")                                                          \
    for (int nl = 0; nl < 4; nl++)                                             \
      bfr[nl] = *(const bf16x8*)(bufB + wno + nl*2048 + lro + (CK));           \
    if (STG) {                                                                 \
      _Pragma("unroll")                                                        \
      for (int i = 0; i < 2; i++)                                              \
        async16(ldsAn + o16[i], Ag + (size_t)aRow[i]*K + kn + aCol[i]);        \
      _Pragma("unroll")                                                        \
      for (int i = 0; i < 4; i++)                                              \
        async16(ldsBn + o16b[i], Bg + (size_t)bRow[i]*K + kn + bCol[i]);       \
    }                                                                          \
    __builtin_amdgcn_sched_barrier(0);                                         \
    __builtin_amdgcn_s_barrier();                                              \
    asm volatile("s_waitcnt lgkmcnt(0)" ::: "memory");                         \
    __builtin_amdgcn_sched_barrier(0);                                         \
    __builtin_amdgcn_s_setprio(1);                                             \
    _Pragma("unroll")                                                          \
    for (int m4 = 0; m4 < 4; m4++)                                             \
      _Pragma("unroll")                                                        \
      for (int n4 = 0; n4 < 4; n4++)                                           \
        acc[m4][n4] = __builtin_amdgcn_mfma_f32_16x16x32_bf16(                 \
            afr[m4], bfr[n4], acc[m4][n4], 0, 0, 0);                           \
    __builtin_amdgcn_s_setprio(0);                                             \
    __builtin_amdgcn_sched_barrier(0);                                         \
    if (WAIT_) { asm volatile("s_waitcnt vmcnt(0)" ::: "memory"); }            \
    __builtin_amdgcn_s_barrier();                                              \
    __builtin_amdgcn_sched_barrier(0);                                         \
  }

template <int K>
__global__ __launch_bounds__(512, 2)
void gemm2_k(const unsigned short* __restrict__ A, const unsigned short* __restrict__ B,
             float* __restrict__ Cf) {
  __shared__ __align__(1024) char lds[98304];
  constexpr int NT = K / 64;
  const int tid = threadIdx.x;
  const int lane = tid & 63, wid = tid >> 6;
  const int wm = wid >> 2, wn = wid & 3;   // 2 x 4 waves, wave tile 64x64
  const int lr = lane & 15;

  const int wg = (blockIdx.x & 7) * 32 + (blockIdx.x >> 3);  // nwg=256
  const int bm = wg >> 2, bn = wg & 3;

  const int swz = (lr & 7) << 4;
  const int colk0 = ((lane >> 4) * 16) ^ swz;
  const int colk1 = (64 + (lane >> 4) * 16) ^ swz;
  const int wmo = wm * 8192, wno = wn * 8192, lro = lr * 128;

  // staging decode: A tile [128 r][128 B] (2 calls/thread), B tile [256 r][128 B] (4 calls)
  int aRow[2], aCol[2], o16[2];
  int bRow[4], bCol[4], o16b[4];
  #pragma unroll
  for (int i = 0; i < 2; i++) {
    int o = (i * 512 + tid) * 16;
    o16[i] = o;
    int r = o >> 7, cb = o & 127;
    aRow[i] = r; aCol[i] = (cb ^ ((r & 7) << 4)) >> 1;
  }
  #pragma unroll
  for (int i = 0; i < 4; i++) {
    int o = (i * 512 + tid) * 16;
    o16b[i] = o;
    int r = o >> 7, cb = o & 127;
    bRow[i] = r; bCol[i] = (cb ^ ((r & 7) << 4)) >> 1;
  }

  const unsigned short* Ag = A + (size_t)bm * 128 * K;
  const unsigned short* Bg = B + (size_t)bn * 256 * K;

  f32x4 acc[4][4];
  #pragma unroll
  for (int m = 0; m < 4; m++)
    #pragma unroll
    for (int n = 0; n < 4; n++) acc[m][n] = (f32x4){0.f, 0.f, 0.f, 0.f};

  // prologue: stage tile 0 into buf0, drain, barrier
  #pragma unroll
  for (int i = 0; i < 2; i++) async16(lds + o16[i],          Ag + (size_t)aRow[i] * K + aCol[i]);
  #pragma unroll
  for (int i = 0; i < 4; i++) async16(lds + 32768 + o16b[i], Bg + (size_t)bRow[i] * K + bCol[i]);
  asm volatile("s_waitcnt vmcnt(0)" ::: "memory");
  __builtin_amdgcn_s_barrier();

  #pragma unroll 1
  for (int t = 0; t < NT; t += 2) {
    {
      const char* bufA = lds;               // cur buf0
      const char* bufB = lds + 32768;
      char* ldsAn = lds + 16384;            // stage into buf1
      char* ldsBn = lds + 32768 + 32768;
      const int kn = ((t + 1) & (NT - 1)) << 6;
      G2PHASE(colk0, 1, 0)
      G2PHASE(colk1, 0, 1)
    }
    {
      const char* bufA = lds + 16384;       // cur buf1
      const char* bufB = lds + 32768 + 32768;
      char* ldsAn = lds;                    // stage into buf0
      char* ldsBn = lds + 32768;
      const int kn = ((t + 2) & (NT - 1)) << 6;
      G2PHASE(colk0, 1, 0)
      G2PHASE(colk1, 0, 1)
    }
  }

  asm volatile("s_waitcnt vmcnt(0)" ::: "memory");

  // epilogue: f32 store
  const int jr = (lane >> 4) * 4;
  #pragma unroll
  for (int m = 0; m < 4; m++) {
    #pragma unroll
    for (int n = 0; n < 4; n++) {
      int col = bn * 256 + wn * 64 + n * 16 + lr;
      #pragma unroll
      for (int j = 0; j < 4; j++) {
        int r = bm * 128 + wm * 64 + m * 16 + jr + j;
        Cf[(size_t)r * HID + col] = acc[m][n][j];
      }
    }
  }
}

extern "C" void kernel_launch(void* const* d_in, const int* in_sizes, int n_in,
                              void* d_out, int out_size, void* d_ws, size_t ws_size,
                              hipStream_t stream) {
  const float* x   = (const float*)d_in[0];
  const float* sm  = (const float*)d_in[1];
  const float* thr = (const float*)d_in[2];
  const float* w1  = (const float*)d_in[3];
  const float* w2  = (const float*)d_in[4];

  float* out_final  = (float*)d_out;
  float* out_scores = out_final + (size_t)NTOK * HID;
  float* out_k      = out_scores + (size_t)NTOK * NEXP;

  char* ws = (char*)d_ws;
  size_t off = 0;
  float* inv_smn = (float*)(ws + off); off += 256;
  float* rwbuf   = (float*)(ws + off); off += (size_t)NTOK * NEXP * 4;
  unsigned short* Xb  = (unsigned short*)(ws + off); off += (size_t)NTOK * HID * 2;
  unsigned short* W1T = (unsigned short*)(ws + off); off += (size_t)NBIG * HID * 2;
  unsigned short* W2T = (unsigned short*)(ws + off); off += (size_t)HID * NBIG * 2;
  unsigned short* H   = (unsigned short*)(ws + off); off += (size_t)NTOK * NBIG * 2;

  simnorm_kernel<<<1, 256, 0, stream>>>(sm, inv_smn);
  gate_kernel<<<NTOK, 256, 0, stream>>>(x, sm, thr, inv_smn, out_scores, out_k, rwbuf, Xb);
  transpose_cast_kernel<<<dim3(ISZ / 32, HID / 32, NEXP), 256, 0, stream>>>(
      w1, W1T, HID, ISZ, HID, HID * ISZ, ISZ * HID);
  transpose_cast_kernel<<<dim3(HID / 32, ISZ / 32, NEXP), 256, 0, stream>>>(
      w2, W2T, ISZ, HID, NBIG, ISZ * HID, ISZ);

  // H = gelu(Xb @ W1T^T) * rw   [8192 x 4096], 512 blocks
  gemm1_k<HID, HID, 16><<<512, 512, 0, stream>>>(Xb, W1T, H, rwbuf);
  // final = H @ W2T^T            [8192 x 1024], 256 blocks (128x256 tiles)
  gemm2_k<NBIG><<<256, 512, 0, stream>>>(H, W2T, out_final);
}